// Round 5
// baseline (1595.735 us; speedup 1.0000x reference)
//
#include <hip/hip_runtime.h>
#include <stdint.h>

typedef short bf16x8 __attribute__((ext_vector_type(8)));
typedef float f32x4  __attribute__((ext_vector_type(4)));
typedef unsigned short u16;

#define NBATCH 2048
#define NT 200

// MFMA with weight operand FORCED into AGPR class at every use.
#define MFMA_AG(accv, av, wfrag) \
  asm("v_mfma_f32_16x16x32_bf16 %0, %1, %2, %0" : "+v"(accv) : "v"(av), "a"(wfrag))
// MFMA with weight pinned in VGPR class.
#define MFMA_AV(accv, av, wfrag) \
  asm("v_mfma_f32_16x16x32_bf16 %0, %1, %2, %0" : "+v"(accv) : "v"(av), "v"(wfrag))
#define SEED_A(x) asm volatile("" : "+a"(x))

// ---- ws layout (total = 215,482,368 B) ----
#define OFF_HN1   209715200ull
#define OFF_HN2   211812352ull
#define OFF_ZC    213909504ull

__device__ __forceinline__ short f2bf(float f){
  union { float f; uint32_t u; } v; v.f = f;
  uint32_t u = v.u;
  u += 0x7fffu + ((u >> 16) & 1u);   // round-to-nearest-even
  return (short)(u >> 16);
}
__device__ __forceinline__ float sigm(float x){ return 1.0f / (1.0f + __expf(-x)); }
__device__ __forceinline__ float tanh_(float x){
  float t = __expf(-2.0f * fabsf(x));
  float r = (1.0f - t) / (1.0f + t);
  return x < 0.0f ? -r : r;
}

// ================= weight prep (layouts for 256-thread consumers) =================
// consumer lane decode: wv=tid>>6 (0..3), ln=tid&63, lr=ln&15, lk=ln>>4
// L1 frag (d,g,u,kt): n=g*128+wv*32+u*16+lr, k=kt*32+lk*8+i, src whh[n*128+k]
// L2 frag (d,g,u,kt): kt<8 -> wih[n*256+kt*32+lk*8+i]; kt>=8 -> whh[n*128+(kt-8)*32+lk*8+i]
__global__ void prep_l12(const float* __restrict__ l1hf, const float* __restrict__ l1hb,
                         const float* __restrict__ l2wf, const float* __restrict__ l2hf,
                         const float* __restrict__ l2wb, const float* __restrict__ l2hb,
                         u16* __restrict__ wl1, u16* __restrict__ wl2)
{
  int idx = blockIdx.x * 256 + threadIdx.x;     // 65536 total
  int tid, wv, ln, lr, lk;
  if (idx < 16384){                             // L1: 2 dirs * 32 frags * 256 threads
    tid = idx & 255; int r = idx >> 8;          // r = d*32 + g*8 + u*4 + kt
    int kt = r & 3, u = (r >> 2) & 1, g = (r >> 3) & 3, d = r >> 5;
    wv = tid >> 6; ln = tid & 63; lr = ln & 15; lk = ln >> 4;
    const float* whh = d ? l1hb : l1hf;
    int n = g * 128 + wv * 32 + u * 16 + lr;
    const float* s = whh + (size_t)n * 128 + kt * 32 + lk * 8;
    bf16x8 w;
#pragma unroll
    for (int i = 0; i < 8; ++i) w[i] = f2bf(s[i]);
    *(bf16x8*)(wl1 + (size_t)idx * 8) = w;
  } else {                                      // L2: 2 dirs * 96 frags * 256 threads
    int j = idx - 16384;
    tid = j & 255; int r = j >> 8;              // r = d*96 + (g*2+u)*12 + kt
    int kt = r % 12, q2 = r / 12;
    int u = q2 & 1, g = (q2 >> 1) & 3, d = q2 >> 3;
    wv = tid >> 6; ln = tid & 63; lr = ln & 15; lk = ln >> 4;
    const float* wih = d ? l2wb : l2wf;
    const float* whh = d ? l2hb : l2hf;
    int n = g * 128 + wv * 32 + u * 16 + lr;
    const float* s = (kt < 8) ? (wih + (size_t)n * 256 + kt * 32 + lk * 8)
                              : (whh + (size_t)n * 128 + (kt - 8) * 32 + lk * 8);
    bf16x8 w;
#pragma unroll
    for (int i = 0; i < 8; ++i) w[i] = f2bf(s[i]);
    *(bf16x8*)(wl2 + (size_t)j * 8) = w;
  }
}

__global__ void prep_dec(const float* __restrict__ g1whh, const float* __restrict__ g2wih,
                         const float* __restrict__ g2whh,
                         u16* __restrict__ wd1, u16* __restrict__ wd2i, u16* __restrict__ wd2h)
{
  int idx = blockIdx.x * 256 + threadIdx.x;     // 10752 total
  if (idx < 6144){                              // W1: 3g*2u*4kt * 256
    int tid = idx & 255; int r = idx >> 8;      // r = g*8 + u*4 + kt
    int kt = r & 3, u = (r >> 2) & 1, g = r >> 3;
    int wv = tid >> 6, ln = tid & 63, lr = ln & 15, lk = ln >> 4;
    int n = g * 128 + wv * 32 + u * 16 + lr;
    const float* s = g1whh + (size_t)n * 128 + kt * 32 + lk * 8;
    bf16x8 w;
#pragma unroll
    for (int i = 0; i < 8; ++i) w[i] = f2bf(s[i]);
    *(bf16x8*)(wd1 + (size_t)idx * 8) = w;
  } else if (idx < 9216){                       // Wi2: 3g*4kt * 256
    int j = idx - 6144;
    int tid = j & 255, r = j >> 8;
    int kt = r & 3, g = r >> 2;
    int wv = tid >> 6, ln = tid & 63, lr = ln & 15, lk = ln >> 4;
    int jj = wv * 16 + lr;
    bf16x8 w;
#pragma unroll
    for (int i = 0; i < 8; ++i){
      int k = kt * 32 + lk * 8 + i;
      w[i] = (jj < 50) ? f2bf(g2wih[(size_t)(g * 50 + jj) * 128 + k]) : (short)0;
    }
    *(bf16x8*)(wd2i + (size_t)j * 8) = w;
  } else {                                      // Wh2: 3g*2kt * 256
    int j = idx - 9216;
    int tid = j & 255, r = j >> 8;
    int kt = r & 1, g = r >> 1;
    int wv = tid >> 6, ln = tid & 63, lr = ln & 15, lk = ln >> 4;
    int jj = wv * 16 + lr;
    bf16x8 w;
#pragma unroll
    for (int i = 0; i < 8; ++i){
      int k = kt * 32 + lk * 8 + i;
      w[i] = (jj < 50 && k < 50) ? f2bf(g2whh[(size_t)(g * 50 + jj) * 50 + k]) : (short)0;
    }
    *(bf16x8*)(wd2h + (size_t)j * 8) = w;
  }
}

__global__ void prep_fcT(const float* __restrict__ fc1w, const float* __restrict__ fc2w,
                         float* __restrict__ fc1wT, float* __restrict__ fc2wT)
{
  int idx = blockIdx.x * 256 + threadIdx.x;     // 81920 total
  if (idx < 65536){
    int n = idx & 255, k = idx >> 8;
    fc1wT[(size_t)k * 256 + n] = fc1w[(size_t)n * 256 + k];
  } else {
    int j = idx - 65536;
    int m = j & 63, k = j >> 6;
    fc2wT[(size_t)k * 64 + m] = fc2w[(size_t)m * 256 + k];
  }
}

// ================= node embedding mean =================
__global__ void k_node(const int* __restrict__ nd, const float* __restrict__ emb,
                       float* __restrict__ ne){
  int t = blockIdx.x * 256 + threadIdx.x;
  if (t >= NBATCH * 64) return;
  int row = t >> 6, e = t & 63;
  int i0 = nd[row * 2], i1 = nd[row * 2 + 1];
  ne[t] = 0.5f * (emb[(size_t)i0 * 64 + e] + emb[(size_t)i1 * 64 + e]);
}

// ================= BiLSTM layer 1: 256 thr, 1 wave/SIMD, all W in AGPR =================
__global__ __launch_bounds__(256) __attribute__((amdgpu_waves_per_eu(1, 1))) void k_l1(
    const float* __restrict__ edge, const u16* __restrict__ wl1,
    const float* __restrict__ wih_f, const float* __restrict__ b_f,
    const float* __restrict__ wih_b, const float* __restrict__ b_b,
    u16* __restrict__ h1out, float* __restrict__ hn1)
{
  const int bid = blockIdx.x;
  const int dir = bid >> 7;
  const int b0  = (bid & 127) * 16;
  const float* wih = dir ? wih_b : wih_f;
  const float* bia = dir ? b_b  : b_f;

  const int tid = threadIdx.x;
  const int wv  = tid >> 6;
  const int ln  = tid & 63;
  const int lr  = ln & 15;
  const int lk  = ln >> 4;

  __shared__ __align__(16) short hbf[2][16 * 128];   // 256B rows, XOR-swizzled
  __shared__ float xall[16][NT];

  bf16x8 W[4][2][4];                                 // 32 frags = 128 AGPR
  const u16* wb = wl1 + (size_t)dir * 32 * 256 * 8;
  float wv_[4][2], bv_[4][2];
#pragma unroll
  for (int g = 0; g < 4; ++g)
#pragma unroll
    for (int u = 0; u < 2; ++u){
      int n = g * 128 + wv * 32 + u * 16 + lr;
      wv_[g][u] = wih[n];
      bv_[g][u] = bia[n];
#pragma unroll
      for (int kt = 0; kt < 4; ++kt){
        W[g][u][kt] = *(const bf16x8*)(wb + ((size_t)((g * 2 + u) * 4 + kt) * 256 + tid) * 8);
        SEED_A(W[g][u][kt]);
      }
    }
  for (int i = tid; i < 16 * 128; i += 256) hbf[0][i] = 0;
  for (int i = tid; i < 16 * NT; i += 256){
    int r = i / NT, t = i - r * NT;
    xall[r][t] = edge[(b0 + r) * NT + t];
  }
  float cst[2][4] = {{0.f,0.f,0.f,0.f},{0.f,0.f,0.f,0.f}};
  float hseg[2][4] = {{0.f,0.f,0.f,0.f},{0.f,0.f,0.f,0.f}};
  __syncthreads();

  for (int s = 0; s < NT; ++s){
    const int p = s & 1;
    const int t = dir ? (NT - 1 - s) : s;

    const char* hb = (const char*)hbf + p * (16 * 256);
    f32x4 acc[4][2];
    float xq[4];
#pragma unroll
    for (int q = 0; q < 4; ++q) xq[q] = xall[lk * 4 + q][t];
#pragma unroll
    for (int g = 0; g < 4; ++g)
#pragma unroll
      for (int u = 0; u < 2; ++u)
#pragma unroll
        for (int q = 0; q < 4; ++q) acc[g][u][q] = fmaf(xq[q], wv_[g][u], bv_[g][u]);
#pragma unroll
    for (int kt = 0; kt < 4; ++kt){
      int off = lr * 256 + ((kt * 64 + lk * 16) ^ ((lr & 7) << 4));
      bf16x8 a = *(const bf16x8*)(hb + off);
#pragma unroll
      for (int g = 0; g < 4; ++g)
#pragma unroll
        for (int u = 0; u < 2; ++u) MFMA_AG(acc[g][u], a, W[g][u][kt]);
    }
    char* hbw = (char*)hbf + (p ^ 1) * (16 * 256);
#pragma unroll
    for (int u = 0; u < 2; ++u)
#pragma unroll
      for (int q = 0; q < 4; ++q){
        float iv = sigm(acc[0][u][q]);
        float fv = sigm(acc[1][u][q]);
        float gv = tanh_(acc[2][u][q]);
        float ov = sigm(acc[3][u][q]);
        cst[u][q] = fv * cst[u][q] + iv * gv;
        hseg[u][q] = ov * tanh_(cst[u][q]);
        short hv = f2bf(hseg[u][q]);
        int r = lk * 4 + q, j = wv * 32 + u * 16 + lr;
        h1out[((size_t)t * NBATCH + b0 + r) * 256 + dir * 128 + j] = (u16)hv;
        *(short*)(hbw + r * 256 + ((2 * j) ^ ((r & 7) << 4))) = hv;
      }
    __syncthreads();
  }
#pragma unroll
  for (int u = 0; u < 2; ++u)
#pragma unroll
    for (int q = 0; q < 4; ++q)
      hn1[((size_t)dir * NBATCH + b0 + lk * 4 + q) * 128 + wv * 32 + u * 16 + lr] = hseg[u][q];
}

// ===== BiLSTM layer 2: 256 thr, 1 wave/SIMD; 64 frags AGPR + 32 frags VGPR, no W in LDS =====
__global__ __launch_bounds__(256) __attribute__((amdgpu_waves_per_eu(1, 1))) void k_l2(
    const u16* __restrict__ h1out, const u16* __restrict__ wl2,
    const float* __restrict__ b_f, const float* __restrict__ b_b,
    float* __restrict__ hn2)
{
  const int bid = blockIdx.x;
  const int dir = bid >> 7;
  const int b0  = (bid & 127) * 16;
  const float* bia = dir ? b_b : b_f;

  const int tid = threadIdx.x;
  const int wv  = tid >> 6;
  const int ln  = tid & 63;
  const int lr  = ln & 15;
  const int lk  = ln >> 4;

  __shared__ __align__(16) short Ab[2][16 * 384];  // 768B rows: x[0,512) | h[512,768), swizzled

  bf16x8 Wa[4][2][8];    // kt 0..7  (x-part)  -> 64 frags = 256 AGPR
  bf16x8 Wv[4][2][4];    // kt 8..11 (h-part)  -> 32 frags = 128 VGPR
  const u16* wb = wl2 + (size_t)dir * 96 * 256 * 8;
  float bv_[4][2];
#pragma unroll
  for (int g = 0; g < 4; ++g)
#pragma unroll
    for (int u = 0; u < 2; ++u){
      bv_[g][u] = bia[g * 128 + wv * 32 + u * 16 + lr];
#pragma unroll
      for (int kt = 0; kt < 8; ++kt){
        Wa[g][u][kt] = *(const bf16x8*)(wb + ((size_t)((g * 2 + u) * 12 + kt) * 256 + tid) * 8);
        SEED_A(Wa[g][u][kt]);
      }
#pragma unroll
      for (int kt = 0; kt < 4; ++kt)
        Wv[g][u][kt] = *(const bf16x8*)(wb + ((size_t)((g * 2 + u) * 12 + 8 + kt) * 256 + tid) * 8);
    }
  // zero h region of buf0; stage x(t0) into buf0
  for (int i = tid; i < 16 * 128; i += 256){
    int r = i >> 7, j = i & 127;
    *(short*)((char*)Ab + r * 768 + ((512 + 2 * j) ^ ((r & 7) << 4))) = 0;
  }
  const int sr = tid >> 4, sg = tid & 15;
  {
    int t0 = dir ? NT - 1 : 0;
    bf16x8 v0 = *(const bf16x8*)(h1out + ((size_t)t0 * NBATCH + b0 + sr) * 256 + sg * 8);
    bf16x8 v1 = *(const bf16x8*)(h1out + ((size_t)t0 * NBATCH + b0 + sr) * 256 + 128 + sg * 8);
    *(bf16x8*)((char*)Ab + sr * 768 + ((sg * 16) ^ ((sr & 7) << 4))) = v0;
    *(bf16x8*)((char*)Ab + sr * 768 + (((256 + sg * 16)) ^ ((sr & 7) << 4))) = v1;
  }
  float cst[2][4] = {{0.f,0.f,0.f,0.f},{0.f,0.f,0.f,0.f}};
  float hseg[2][4] = {{0.f,0.f,0.f,0.f},{0.f,0.f,0.f,0.f}};
  __syncthreads();

  for (int s = 0; s < NT; ++s){
    const int p = s & 1;
    const int t = dir ? (NT - 1 - s) : s;
    const int tn = dir ? (t > 0 ? t - 1 : 0) : (t < NT - 1 ? t + 1 : NT - 1);
    bf16x8 xr0 = *(const bf16x8*)(h1out + ((size_t)tn * NBATCH + b0 + sr) * 256 + sg * 8);
    bf16x8 xr1 = *(const bf16x8*)(h1out + ((size_t)tn * NBATCH + b0 + sr) * 256 + 128 + sg * 8);

    const char* ab = (const char*)Ab + p * (16 * 768);
    f32x4 acc[4][2];
#pragma unroll
    for (int g = 0; g < 4; ++g)
#pragma unroll
      for (int u = 0; u < 2; ++u)
#pragma unroll
        for (int q = 0; q < 4; ++q) acc[g][u][q] = bv_[g][u];
#pragma unroll
    for (int kt = 0; kt < 8; ++kt){
      int off = lr * 768 + ((kt * 64 + lk * 16) ^ ((lr & 7) << 4));
      bf16x8 a = *(const bf16x8*)(ab + off);
#pragma unroll
      for (int g = 0; g < 4; ++g)
#pragma unroll
        for (int u = 0; u < 2; ++u) MFMA_AG(acc[g][u], a, Wa[g][u][kt]);
    }
#pragma unroll
    for (int kt = 0; kt < 4; ++kt){
      int off = lr * 768 + (((8 + kt) * 64 + lk * 16) ^ ((lr & 7) << 4));
      bf16x8 a = *(const bf16x8*)(ab + off);
#pragma unroll
      for (int g = 0; g < 4; ++g)
#pragma unroll
        for (int u = 0; u < 2; ++u) MFMA_AV(acc[g][u], a, Wv[g][u][kt]);
    }
    char* abw = (char*)Ab + (p ^ 1) * (16 * 768);
#pragma unroll
    for (int u = 0; u < 2; ++u)
#pragma unroll
      for (int q = 0; q < 4; ++q){
        float iv = sigm(acc[0][u][q]);
        float fv = sigm(acc[1][u][q]);
        float gv = tanh_(acc[2][u][q]);
        float ov = sigm(acc[3][u][q]);
        cst[u][q] = fv * cst[u][q] + iv * gv;
        hseg[u][q] = ov * tanh_(cst[u][q]);
        int r = lk * 4 + q, j = wv * 32 + u * 16 + lr;
        *(short*)(abw + r * 768 + ((512 + 2 * j) ^ ((r & 7) << 4))) = f2bf(hseg[u][q]);
      }
    *(bf16x8*)(abw + sr * 768 + ((sg * 16) ^ ((sr & 7) << 4))) = xr0;
    *(bf16x8*)(abw + sr * 768 + (((256 + sg * 16)) ^ ((sr & 7) << 4))) = xr1;
    __syncthreads();
  }
#pragma unroll
  for (int u = 0; u < 2; ++u)
#pragma unroll
    for (int q = 0; q < 4; ++q)
      hn2[((size_t)dir * NBATCH + b0 + lk * 4 + q) * 128 + wv * 32 + u * 16 + lr] = hseg[u][q];
}

// ================= FC =================
__global__ __launch_bounds__(256) void k_fc(
    const float* __restrict__ hn1, const float* __restrict__ hn2,
    const float* __restrict__ fc1wT, const float* __restrict__ fc1b,
    const float* __restrict__ fc2wT, const float* __restrict__ fc2b,
    const float* __restrict__ ne, float* __restrict__ hidden)
{
  __shared__ float X[16][256];
  __shared__ float Y[16][256];
  const int b0 = blockIdx.x * 16;
  const int tid = threadIdx.x;
  for (int i = tid; i < 16 * 256; i += 256){
    int rr = i >> 8, cc = i & 255;
    size_t o = (size_t)(b0 + rr) * 256 + cc;
    X[rr][cc] = hn1[o] + hn2[o];
  }
  __syncthreads();
  {
    const int n = tid;
    float a[16];
#pragma unroll
    for (int r = 0; r < 16; ++r) a[r] = fc1b[n];
    for (int k = 0; k < 256; ++k){
      float w = fc1wT[(size_t)k * 256 + n];
#pragma unroll
      for (int r = 0; r < 16; ++r) a[r] = fmaf(X[r][k], w, a[r]);
    }
#pragma unroll
    for (int r = 0; r < 16; ++r) Y[r][n] = sigm(a[r]);
  }
  __syncthreads();
  {
    const int m = tid & 63, rg = tid >> 6;
    float a2[4];
#pragma unroll
    for (int q = 0; q < 4; ++q) a2[q] = fc2b[m];
    for (int k = 0; k < 256; ++k){
      float w = fc2wT[(size_t)k * 64 + m];
#pragma unroll
      for (int q = 0; q < 4; ++q) a2[q] = fmaf(Y[rg * 4 + q][k], w, a2[q]);
    }
#pragma unroll
    for (int q = 0; q < 4; ++q)
      hidden[(size_t)(b0 + rg * 4 + q) * 128 + m] = sigm(a2[q]);
  }
  for (int i = tid; i < 16 * 64; i += 256){
    int rr = i >> 6, e = i & 63;
    hidden[(size_t)(b0 + rr) * 128 + 64 + e] = ne[(size_t)(b0 + rr) * 64 + e];
  }
}

// ===== decoder: 256 thr, BC=8 (rows 8..15 zero-padded), GRU2 across all 4 waves =====
__global__ __launch_bounds__(256) __attribute__((amdgpu_waves_per_eu(1, 1))) void k_dec(
    const float* __restrict__ edge, const float* __restrict__ hidden,
    const float* __restrict__ g1wih, const float* __restrict__ g1bih,
    const float* __restrict__ g1bhh, const u16* __restrict__ wd1,
    const float* __restrict__ g2bih, const float* __restrict__ g2bhh,
    const u16* __restrict__ wd2i, const u16* __restrict__ wd2h,
    const float* __restrict__ decw, const float* __restrict__ decb,
    float* __restrict__ out)
{
  const int b0 = blockIdx.x * 8;       // 256 blocks x 8 rows
  const int tid = threadIdx.x;
  const int wv  = tid >> 6;
  const int ln  = tid & 63;
  const int lr  = ln & 15;
  const int lk  = ln >> 4;

  __shared__ __align__(16) short h1bf[2][16 * 128];
  __shared__ __align__(16) short h2bf[2][16 * 64];
  __shared__ float part[2][4][16];

  bf16x8 W1[3][2][4];                 // 24 frags = 96 AGPR
  float wih1v[3][2], bih1v[3][2], bhh1v[3][2];
#pragma unroll
  for (int g = 0; g < 3; ++g)
#pragma unroll
    for (int u = 0; u < 2; ++u){
      int n = g * 128 + wv * 32 + u * 16 + lr;
      wih1v[g][u] = g1wih[n];
      bih1v[g][u] = g1bih[n];
      bhh1v[g][u] = g1bhh[n];
#pragma unroll
      for (int kt = 0; kt < 4; ++kt){
        W1[g][u][kt] = *(const bf16x8*)(wd1 + ((size_t)((g * 2 + u) * 4 + kt) * 256 + tid) * 8);
        SEED_A(W1[g][u][kt]);
      }
    }
  bf16x8 Wi2[3][4], Wh2[3][2];        // 18 frags = 72 AGPR
  float bih2v[3], bhh2v[3], dwv;
  const int jj = wv * 16 + lr;
  {
    bool nv_ = (jj < 50);
    dwv = nv_ ? decw[jj] : 0.f;
#pragma unroll
    for (int g = 0; g < 3; ++g){
      bih2v[g] = nv_ ? g2bih[g * 50 + jj] : 0.f;
      bhh2v[g] = nv_ ? g2bhh[g * 50 + jj] : 0.f;
#pragma unroll
      for (int kt = 0; kt < 4; ++kt){
        Wi2[g][kt] = *(const bf16x8*)(wd2i + ((size_t)(g * 4 + kt) * 256 + tid) * 8);
        SEED_A(Wi2[g][kt]);
      }
#pragma unroll
      for (int kt = 0; kt < 2; ++kt){
        Wh2[g][kt] = *(const bf16x8*)(wd2h + ((size_t)(g * 2 + kt) * 256 + tid) * 8);
        SEED_A(Wh2[g][kt]);
      }
    }
  }
  // init (rows >= 8 are zero pad)
  float h1s[2][4], h2s[4] = {0.f, 0.f, 0.f, 0.f}, e4[4];
#pragma unroll
  for (int u = 0; u < 2; ++u)
#pragma unroll
    for (int q = 0; q < 4; ++q){
      int r = lk * 4 + q, j = wv * 32 + u * 16 + lr;
      h1s[u][q] = (r < 8) ? hidden[(size_t)(b0 + r) * 128 + j] : 0.f;
      *(short*)((char*)h1bf + r * 256 + ((2 * j) ^ ((r & 7) << 4))) = f2bf(h1s[u][q]);
    }
#pragma unroll
  for (int q = 0; q < 4; ++q){
    int r = lk * 4 + q;
    e4[q] = (r < 8) ? edge[(b0 + r) * NT + NT - 1] : 0.f;
  }
  for (int i = tid; i < 16 * 64; i += 256) h2bf[0][i] = 0;
  const float db = decb[0];
  __syncthreads();

  for (int s = 0; s < NT; ++s){
    const int p = s & 1;
    float res_q[4];
    if (s == 0){
#pragma unroll
      for (int q = 0; q < 4; ++q) res_q[q] = e4[q];
    } else {
#pragma unroll
      for (int q = 0; q < 4; ++q){
        int row = lk * 4 + q;
        float sum = part[p][0][row] + part[p][1][row] + part[p][2][row] + part[p][3][row] + db;
        res_q[q] = sigm(sum);
        if (wv == 0 && lr == 0 && row < 8) out[(size_t)(b0 + row) * NT + (s - 1)] = res_q[q];
      }
    }
    // ---- GRU1 (all waves, N=32 slice each) ----
    const char* h1r = (const char*)h1bf + p * (16 * 256);
    f32x4 a1[3][2];
#pragma unroll
    for (int g = 0; g < 3; ++g)
#pragma unroll
      for (int u = 0; u < 2; ++u)
#pragma unroll
        for (int q = 0; q < 4; ++q) a1[g][u][q] = bhh1v[g][u];
#pragma unroll
    for (int kt = 0; kt < 4; ++kt){
      int off = lr * 256 + ((kt * 64 + lk * 16) ^ ((lr & 7) << 4));
      bf16x8 a = *(const bf16x8*)(h1r + off);
#pragma unroll
      for (int g = 0; g < 3; ++g)
#pragma unroll
        for (int u = 0; u < 2; ++u) MFMA_AG(a1[g][u], a, W1[g][u][kt]);
    }
    char* h1w = (char*)h1bf + (p ^ 1) * (16 * 256);
#pragma unroll
    for (int u = 0; u < 2; ++u)
#pragma unroll
      for (int q = 0; q < 4; ++q){
        float res = res_q[q];
        float rv = sigm(fmaf(res, wih1v[0][u], bih1v[0][u]) + a1[0][u][q]);
        float zv = sigm(fmaf(res, wih1v[1][u], bih1v[1][u]) + a1[1][u][q]);
        float nv = tanh_(fmaf(res, wih1v[2][u], bih1v[2][u]) + rv * a1[2][u][q]);
        h1s[u][q] = (1.f - zv) * nv + zv * h1s[u][q];
        int r = lk * 4 + q, j = wv * 32 + u * 16 + lr;
        *(short*)(h1w + r * 256 + ((2 * j) ^ ((r & 7) << 4))) = f2bf(h1s[u][q]);
      }
    __syncthreads();   // A: new h1 visible
    // ---- GRU2 (all waves, N=16 slice of padded 64) ----
    {
      f32x4 gi0, gi1, gi2v, gh0, gh1, gh2v;
#pragma unroll
      for (int q = 0; q < 4; ++q){
        gi0[q] = bih2v[0]; gi1[q] = bih2v[1]; gi2v[q] = bih2v[2];
        gh0[q] = bhh2v[0]; gh1[q] = bhh2v[1]; gh2v[q] = bhh2v[2];
      }
      const char* h1n = (const char*)h1bf + (p ^ 1) * (16 * 256);
#pragma unroll
      for (int kt = 0; kt < 4; ++kt){
        int off = lr * 256 + ((kt * 64 + lk * 16) ^ ((lr & 7) << 4));
        bf16x8 a = *(const bf16x8*)(h1n + off);
        MFMA_AG(gi0,  a, Wi2[0][kt]);
        MFMA_AG(gi1,  a, Wi2[1][kt]);
        MFMA_AG(gi2v, a, Wi2[2][kt]);
      }
      const char* h2r = (const char*)h2bf + p * (16 * 128);
#pragma unroll
      for (int kt = 0; kt < 2; ++kt){
        int off = lr * 128 + ((kt * 64 + lk * 16) ^ ((lr & 7) << 4));
        bf16x8 a = *(const bf16x8*)(h2r + off);
        MFMA_AG(gh0,  a, Wh2[0][kt]);
        MFMA_AG(gh1,  a, Wh2[1][kt]);
        MFMA_AG(gh2v, a, Wh2[2][kt]);
      }
      char* h2w = (char*)h2bf + (p ^ 1) * (16 * 128);
      float pd[4];
#pragma unroll
      for (int q = 0; q < 4; ++q){
        float r2 = sigm(gi0[q] + gh0[q]);
        float z2 = sigm(gi1[q] + gh1[q]);
        float n2 = tanh_(gi2v[q] + r2 * gh2v[q]);
        h2s[q] = (1.f - z2) * n2 + z2 * h2s[q];
        pd[q] = h2s[q] * dwv;
        int r = lk * 4 + q, j = wv * 16 + lr;
        *(short*)(h2w + r * 128 + ((2 * j) ^ ((r & 7) << 4))) = f2bf(h2s[q]);
      }
#pragma unroll
      for (int m = 1; m < 16; m <<= 1){
#pragma unroll
        for (int q = 0; q < 4; ++q) pd[q] += __shfl_xor(pd[q], m);
      }
      if (lr == 0){
#pragma unroll
        for (int q = 0; q < 4; ++q) part[p ^ 1][wv][lk * 4 + q] = pd[q];
      }
    }
    __syncthreads();   // B: h2/part ready
  }
  if (wv == 0 && lr == 0){
#pragma unroll
    for (int q = 0; q < 4; ++q){
      int row = lk * 4 + q;
      if (row < 8){
        float sum = part[0][0][row] + part[0][1][row] + part[0][2][row] + part[0][3][row] + db;
        out[(size_t)(b0 + row) * NT + (NT - 1)] = sigm(sum);
      }
    }
  }
}

// ================= launch =================
extern "C" void kernel_launch(void* const* d_in, const int* in_sizes, int n_in,
                              void* d_out, int out_size, void* d_ws, size_t ws_size,
                              hipStream_t stream)
{
  (void)in_sizes; (void)n_in; (void)out_size; (void)ws_size;
  const int*   nd    = (const int*)  d_in[0];
  const float* edge  = (const float*)d_in[1];
  const float* emb   = (const float*)d_in[2];
  const float* l1wf  = (const float*)d_in[3];
  const float* l1hf  = (const float*)d_in[4];
  const float* l1bf  = (const float*)d_in[5];
  const float* l1wb  = (const float*)d_in[6];
  const float* l1hb  = (const float*)d_in[7];
  const float* l1bb  = (const float*)d_in[8];
  const float* l2wf  = (const float*)d_in[9];
  const float* l2hf  = (const float*)d_in[10];
  const float* l2bf  = (const float*)d_in[11];
  const float* l2wb  = (const float*)d_in[12];
  const float* l2hb  = (const float*)d_in[13];
  const float* l2bb  = (const float*)d_in[14];
  const float* fc1w  = (const float*)d_in[15];
  const float* fc1b  = (const float*)d_in[16];
  const float* fc2w  = (const float*)d_in[17];
  const float* fc2b  = (const float*)d_in[18];
  const float* g1wih = (const float*)d_in[19];
  const float* g1whh = (const float*)d_in[20];
  const float* g1bih = (const float*)d_in[21];
  const float* g1bhh = (const float*)d_in[22];
  const float* g2wih = (const float*)d_in[23];
  const float* g2whh = (const float*)d_in[24];
  const float* g2bih = (const float*)d_in[25];
  const float* g2bhh = (const float*)d_in[26];
  const float* decw  = (const float*)d_in[27];
  const float* decb  = (const float*)d_in[28];

  char* ws = (char*)d_ws;
  u16*   h1out  = (u16*)ws;
  u16*   wd1    = (u16*)ws;
  u16*   wd2i   = (u16*)(ws + 98304);
  u16*   wd2h   = (u16*)(ws + 147456);
  float* fc1wT  = (float*)(ws + 262144);
  float* fc2wT  = (float*)(ws + 524288);
  float* hn1    = (float*)(ws + OFF_HN1);
  float* hn2    = (float*)(ws + OFF_HN2);
  u16*   wl2    = (u16*)(ws + OFF_ZC);
  u16*   wl1    = (u16*)(ws + OFF_ZC + 786432);
  float* ne     = (float*)(ws + OFF_ZC);
  float* hidden = (float*)(ws + OFF_ZC + 524288);

  prep_l12<<<dim3(256), dim3(256), 0, stream>>>(l1hf, l1hb, l2wf, l2hf, l2wb, l2hb, wl1, wl2);
  k_l1<<<dim3(256), dim3(256), 0, stream>>>(edge, wl1, l1wf, l1bf, l1wb, l1bb, h1out, hn1);
  k_l2<<<dim3(256), dim3(256), 0, stream>>>(h1out, wl2, l2bf, l2bb, hn2);
  prep_dec<<<dim3(42), dim3(256), 0, stream>>>(g1whh, g2wih, g2whh, wd1, wd2i, wd2h);
  prep_fcT<<<dim3(320), dim3(256), 0, stream>>>(fc1w, fc2w, fc1wT, fc2wT);
  k_node<<<dim3(512), dim3(256), 0, stream>>>(nd, emb, ne);
  k_fc<<<dim3(128), dim3(256), 0, stream>>>(hn1, hn2, fc1wT, fc1b, fc2wT, fc2b, ne, hidden);
  k_dec<<<dim3(256), dim3(256), 0, stream>>>(edge, hidden, g1wih, g1bih, g1bhh, wd1,
                                             g2bih, g2bhh, wd2i, wd2h, decw, decb,
                                             (float*)d_out);
}

// Round 6
// 1056.610 us; speedup vs baseline: 1.5102x; 1.5102x over previous
//
#include <hip/hip_runtime.h>
#include <stdint.h>

typedef short bf16x8 __attribute__((ext_vector_type(8)));
typedef float f32x4  __attribute__((ext_vector_type(4)));
typedef unsigned short u16;

#define NBATCH 2048
#define NT 200

// MFMA with weight operand FORCED into AGPR class at every use.
#define MFMA_AG(accv, av, wfrag) \
  asm("v_mfma_f32_16x16x32_bf16 %0, %1, %2, %0" : "+v"(accv) : "v"(av), "a"(wfrag))
#define SEED_A(x) asm volatile("" : "+a"(x))

// ---- ws layout (total = 215,482,368 B) ----
#define OFF_HN1   209715200ull
#define OFF_HN2   211812352ull
#define OFF_ZC    213909504ull

__device__ __forceinline__ short f2bf(float f){
  union { float f; uint32_t u; } v; v.f = f;
  uint32_t u = v.u;
  u += 0x7fffu + ((u >> 16) & 1u);   // round-to-nearest-even
  return (short)(u >> 16);
}
// Fast activations: v_rcp instead of the ~12-op precise-division sequence.
__device__ __forceinline__ float sigm(float x){
  return __builtin_amdgcn_rcpf(1.0f + __expf(-x));
}
__device__ __forceinline__ float tanh_(float x){
  // tanh(x) = 1 - 2/(exp(2x)+1); exact at +-inf, ~1ulp elsewhere, branch-free
  return fmaf(-2.0f, __builtin_amdgcn_rcpf(1.0f + __expf(2.0f * x)), 1.0f);
}

// ================= weight prep: fragment layouts (512-thread consumers) =================
__global__ void prep_l12(const float* __restrict__ l1hf, const float* __restrict__ l1hb,
                         const float* __restrict__ l2wf, const float* __restrict__ l2hf,
                         const float* __restrict__ l2wb, const float* __restrict__ l2hb,
                         u16* __restrict__ wl1, u16* __restrict__ wl2)
{
  int idx = blockIdx.x * 256 + threadIdx.x;     // 65536 total
  if (idx < 16384){                             // L1: 2*4*4*512
    int tid = idx & 511, r = idx >> 9;
    int kt = r & 3, g = (r >> 2) & 3, d = r >> 4;
    const float* whh = d ? l1hb : l1hf;
    int wv = tid >> 6, ln = tid & 63, lr = ln & 15, lk = ln >> 4;
    int n = g * 128 + wv * 16 + lr;
    const float* s = whh + (size_t)n * 128 + kt * 32 + lk * 8;
    bf16x8 w;
#pragma unroll
    for (int i = 0; i < 8; ++i) w[i] = f2bf(s[i]);
    *(bf16x8*)(wl1 + (size_t)idx * 8) = w;
  } else {                                      // L2: 2*4*12*512
    int j = idx - 16384;
    int tid = j & 511, r = j >> 9;              // r in 0..95
    int kt = r % 12, rg = r / 12;
    int g = rg & 3, d = rg >> 2;
    const float* wih = d ? l2wb : l2wf;
    const float* whh = d ? l2hb : l2hf;
    int wv = tid >> 6, ln = tid & 63, lr = ln & 15, lk = ln >> 4;
    int n = g * 128 + wv * 16 + lr;
    const float* s = (kt < 8) ? (wih + (size_t)n * 256 + kt * 32 + lk * 8)
                              : (whh + (size_t)n * 128 + (kt - 8) * 32 + lk * 8);
    bf16x8 w;
#pragma unroll
    for (int i = 0; i < 8; ++i) w[i] = f2bf(s[i]);
    *(bf16x8*)(wl2 + (size_t)j * 8) = w;
  }
}

__global__ void prep_dec(const float* __restrict__ g1whh, const float* __restrict__ g2wih,
                         const float* __restrict__ g2whh,
                         u16* __restrict__ wd1, u16* __restrict__ wd2i, u16* __restrict__ wd2h)
{
  int idx = blockIdx.x * 256 + threadIdx.x;     // 10752 total
  if (idx < 6144){                              // W1: 3*4*512
    int tid = idx & 511, r = idx >> 9;
    int kt = r & 3, g = r >> 2;
    int wv = tid >> 6, ln = tid & 63, lr = ln & 15, lk = ln >> 4;
    int n = g * 128 + wv * 16 + lr;
    const float* s = g1whh + (size_t)n * 128 + kt * 32 + lk * 8;
    bf16x8 w;
#pragma unroll
    for (int i = 0; i < 8; ++i) w[i] = f2bf(s[i]);
    *(bf16x8*)(wd1 + (size_t)idx * 8) = w;
  } else if (idx < 9216){                       // Wi2: 3*4*256
    int j = idx - 6144;
    int tid = j & 255, r = j >> 8;
    int kt = r & 3, g = r >> 2;
    int wv = tid >> 6, ln = tid & 63, lr = ln & 15, lk = ln >> 4;
    int jj = wv * 16 + lr;
    bf16x8 w;
#pragma unroll
    for (int i = 0; i < 8; ++i){
      int k = kt * 32 + lk * 8 + i;
      w[i] = (jj < 50) ? f2bf(g2wih[(size_t)(g * 50 + jj) * 128 + k]) : (short)0;
    }
    *(bf16x8*)(wd2i + (size_t)j * 8) = w;
  } else {                                      // Wh2: 3*2*256
    int j = idx - 9216;
    int tid = j & 255, r = j >> 8;
    int kt = r & 1, g = r >> 1;
    int wv = tid >> 6, ln = tid & 63, lr = ln & 15, lk = ln >> 4;
    int jj = wv * 16 + lr;
    bf16x8 w;
#pragma unroll
    for (int i = 0; i < 8; ++i){
      int k = kt * 32 + lk * 8 + i;
      w[i] = (jj < 50 && k < 50) ? f2bf(g2whh[(size_t)(g * 50 + jj) * 50 + k]) : (short)0;
    }
    *(bf16x8*)(wd2h + (size_t)j * 8) = w;
  }
}

__global__ void prep_fcT(const float* __restrict__ fc1w, const float* __restrict__ fc2w,
                         float* __restrict__ fc1wT, float* __restrict__ fc2wT)
{
  int idx = blockIdx.x * 256 + threadIdx.x;     // 81920 total
  if (idx < 65536){
    int n = idx & 255, k = idx >> 8;
    fc1wT[(size_t)k * 256 + n] = fc1w[(size_t)n * 256 + k];
  } else {
    int j = idx - 65536;
    int m = j & 63, k = j >> 6;
    fc2wT[(size_t)k * 64 + m] = fc2w[(size_t)m * 256 + k];
  }
}

// ================= node embedding mean =================
__global__ void k_node(const int* __restrict__ nd, const float* __restrict__ emb,
                       float* __restrict__ ne){
  int t = blockIdx.x * 256 + threadIdx.x;
  if (t >= NBATCH * 64) return;
  int row = t >> 6, e = t & 63;
  int i0 = nd[row * 2], i1 = nd[row * 2 + 1];
  ne[t] = 0.5f * (emb[(size_t)i0 * 64 + e] + emb[(size_t)i1 * 64 + e]);
}

// ================= BiLSTM layer 1 (W in AGPRs via asm-constrained MFMA) =================
__global__ __launch_bounds__(512) __attribute__((amdgpu_waves_per_eu(2, 2))) void k_l1(
    const float* __restrict__ edge, const u16* __restrict__ wl1,
    const float* __restrict__ wih_f, const float* __restrict__ b_f,
    const float* __restrict__ wih_b, const float* __restrict__ b_b,
    u16* __restrict__ h1out, float* __restrict__ hn1)
{
  const int bid = blockIdx.x;
  const int dir = bid >> 7;
  const int b0  = (bid & 127) * 16;
  const float* wih = dir ? wih_b : wih_f;
  const float* bia = dir ? b_b  : b_f;

  const int tid = threadIdx.x;
  const int wv  = tid >> 6;
  const int ln  = tid & 63;
  const int lr  = ln & 15;
  const int lk  = ln >> 4;

  __shared__ __align__(16) short hbf[2][16 * 128];   // 256B rows, XOR-swizzled
  __shared__ float xall[16][NT];

  bf16x8 W[4][4];
  const u16* wb = wl1 + (size_t)dir * 16 * 512 * 8;
  float wv_[4], bv_[4];
#pragma unroll
  for (int g = 0; g < 4; ++g){
    int n = g * 128 + wv * 16 + lr;
    wv_[g] = wih[n];
    bv_[g] = bia[n];
#pragma unroll
    for (int kt = 0; kt < 4; ++kt){
      W[g][kt] = *(const bf16x8*)(wb + ((size_t)(g * 4 + kt) * 512 + tid) * 8);
      SEED_A(W[g][kt]);
    }
  }
  for (int i = tid; i < 16 * 128; i += 512) hbf[0][i] = 0;
  for (int i = tid; i < 16 * NT; i += 512){
    int r = i / NT, t = i - r * NT;
    xall[r][t] = edge[(b0 + r) * NT + t];
  }
  float cst[4] = {0.f, 0.f, 0.f, 0.f};
  float hseg[4] = {0.f, 0.f, 0.f, 0.f};
  __syncthreads();

  for (int s = 0; s < NT; ++s){
    const int p = s & 1;
    const int t = dir ? (NT - 1 - s) : s;

    const char* hb = (const char*)hbf + p * (16 * 256);
    f32x4 acc[4];
    float xq[4];
#pragma unroll
    for (int q = 0; q < 4; ++q) xq[q] = xall[lk * 4 + q][t];
#pragma unroll
    for (int g = 0; g < 4; ++g){
#pragma unroll
      for (int q = 0; q < 4; ++q) acc[g][q] = fmaf(xq[q], wv_[g], bv_[g]);
    }
#pragma unroll
    for (int kt = 0; kt < 4; ++kt){
      int off = lr * 256 + ((kt * 64 + lk * 16) ^ ((lr & 7) << 4));
      bf16x8 a = *(const bf16x8*)(hb + off);
#pragma unroll
      for (int g = 0; g < 4; ++g) MFMA_AG(acc[g], a, W[g][kt]);
    }
    char* hbw = (char*)hbf + (p ^ 1) * (16 * 256);
#pragma unroll
    for (int q = 0; q < 4; ++q){
      float iv = sigm(acc[0][q]);
      float fv = sigm(acc[1][q]);
      float gv = tanh_(acc[2][q]);
      float ov = sigm(acc[3][q]);
      cst[q] = fv * cst[q] + iv * gv;
      hseg[q] = ov * tanh_(cst[q]);
      short hv = f2bf(hseg[q]);
      int r = lk * 4 + q, j = wv * 16 + lr;
      h1out[((size_t)t * NBATCH + b0 + r) * 256 + dir * 128 + j] = (u16)hv;
      *(short*)(hbw + r * 256 + ((2 * j) ^ ((r & 7) << 4))) = hv;
    }
    __syncthreads();
  }
#pragma unroll
  for (int q = 0; q < 4; ++q)
    hn1[((size_t)dir * NBATCH + b0 + lk * 4 + q) * 128 + wv * 16 + lr] = hseg[q];
}

// ===== BiLSTM layer 2: fused K=384; 16 W-frags in LDS (128KB) + 32 W-frags in AGPRs =====
__global__ __launch_bounds__(512) __attribute__((amdgpu_waves_per_eu(2, 2))) void k_l2(
    const u16* __restrict__ h1out, const u16* __restrict__ wl2,
    const float* __restrict__ b_f, const float* __restrict__ b_b,
    float* __restrict__ hn2)
{
  const int bid = blockIdx.x;
  const int dir = bid >> 7;
  const int b0  = (bid & 127) * 16;
  const float* bia = dir ? b_b : b_f;

  const int tid = threadIdx.x;
  const int wv  = tid >> 6;
  const int ln  = tid & 63;
  const int lr  = ln & 15;
  const int lk  = ln >> 4;

  __shared__ __align__(16) short wlds[16 * 512 * 8];   // 128KB: frags (g,kt<4), per-lane 16B
  __shared__ __align__(16) short Ab[2][16 * 384];      // 768B rows: x[0,512) | h[512,768), swizzled

  const u16* wb = wl2 + (size_t)dir * 48 * 512 * 8;
  // stage kt=0..3 (x-part, first half) into LDS — lane-consecutive, conflict-free
#pragma unroll
  for (int f = 0; f < 16; ++f){
    int g = f >> 2, kt = f & 3;
    *(bf16x8*)&wlds[((size_t)f * 512 + tid) * 8] =
        *(const bf16x8*)(wb + ((size_t)(g * 12 + kt) * 512 + tid) * 8);
  }
  // kt=4..11 into AGPRs
  bf16x8 Wa[4][8];
  float bv_[4];
#pragma unroll
  for (int g = 0; g < 4; ++g){
    bv_[g] = bia[g * 128 + wv * 16 + lr];
#pragma unroll
    for (int k8 = 0; k8 < 8; ++k8){
      Wa[g][k8] = *(const bf16x8*)(wb + ((size_t)(g * 12 + 4 + k8) * 512 + tid) * 8);
      SEED_A(Wa[g][k8]);
    }
  }
  for (int i = tid; i < 16 * 128; i += 512){
    int r = i >> 7, j = i & 127;
    *(short*)((char*)Ab + r * 768 + ((512 + 2 * j) ^ ((r & 7) << 4))) = 0;
  }
  const int sr = tid >> 5, sg = tid & 31;
  {
    int t0 = dir ? NT - 1 : 0;
    bf16x8 v = *(const bf16x8*)(h1out + ((size_t)t0 * NBATCH + b0 + sr) * 256 + sg * 8);
    *(bf16x8*)((char*)Ab + sr * 768 + ((sg * 16) ^ ((sr & 7) << 4))) = v;
  }
  float cst[4] = {0.f, 0.f, 0.f, 0.f};
  float hseg[4] = {0.f, 0.f, 0.f, 0.f};
  __syncthreads();

  for (int s = 0; s < NT; ++s){
    const int p = s & 1;
    const int t = dir ? (NT - 1 - s) : s;
    const int tn = dir ? (t > 0 ? t - 1 : 0) : (t < NT - 1 ? t + 1 : NT - 1);
    bf16x8 xr = *(const bf16x8*)(h1out + ((size_t)tn * NBATCH + b0 + sr) * 256 + sg * 8);

    const char* ab = (const char*)Ab + p * (16 * 768);
    f32x4 acc[4];
#pragma unroll
    for (int g = 0; g < 4; ++g){
#pragma unroll
      for (int q = 0; q < 4; ++q) acc[g][q] = bv_[g];
    }
    // kt 0..3: weights from LDS (intrinsic MFMA)
#pragma unroll
    for (int kt = 0; kt < 4; ++kt){
      int off = lr * 768 + ((kt * 64 + lk * 16) ^ ((lr & 7) << 4));
      bf16x8 a = *(const bf16x8*)(ab + off);
#pragma unroll
      for (int g = 0; g < 4; ++g){
        bf16x8 w = *(const bf16x8*)&wlds[((size_t)(g * 4 + kt) * 512 + tid) * 8];
        acc[g] = __builtin_amdgcn_mfma_f32_16x16x32_bf16(a, w, acc[g], 0, 0, 0);
      }
    }
    // kt 4..11: weights resident in AGPRs (asm-constrained MFMA)
#pragma unroll
    for (int k8 = 0; k8 < 8; ++k8){
      int kt = 4 + k8;
      int off = lr * 768 + ((kt * 64 + lk * 16) ^ ((lr & 7) << 4));
      bf16x8 a = *(const bf16x8*)(ab + off);
#pragma unroll
      for (int g = 0; g < 4; ++g) MFMA_AG(acc[g], a, Wa[g][k8]);
    }
    char* abw = (char*)Ab + (p ^ 1) * (16 * 768);
#pragma unroll
    for (int q = 0; q < 4; ++q){
      float iv = sigm(acc[0][q]);
      float fv = sigm(acc[1][q]);
      float gv = tanh_(acc[2][q]);
      float ov = sigm(acc[3][q]);
      cst[q] = fv * cst[q] + iv * gv;
      hseg[q] = ov * tanh_(cst[q]);
      int r = lk * 4 + q, j = wv * 16 + lr;
      *(short*)(abw + r * 768 + ((512 + 2 * j) ^ ((r & 7) << 4))) = f2bf(hseg[q]);
    }
    *(bf16x8*)(abw + sr * 768 + ((sg * 16) ^ ((sr & 7) << 4))) = xr;
    __syncthreads();
  }
#pragma unroll
  for (int q = 0; q < 4; ++q)
    hn2[((size_t)dir * NBATCH + b0 + lk * 4 + q) * 128 + wv * 16 + lr] = hseg[q];
}

// ================= FC =================
__global__ __launch_bounds__(256) void k_fc(
    const float* __restrict__ hn1, const float* __restrict__ hn2,
    const float* __restrict__ fc1wT, const float* __restrict__ fc1b,
    const float* __restrict__ fc2wT, const float* __restrict__ fc2b,
    const float* __restrict__ ne, float* __restrict__ hidden)
{
  __shared__ float X[16][256];
  __shared__ float Y[16][256];
  const int b0 = blockIdx.x * 16;
  const int tid = threadIdx.x;
  for (int i = tid; i < 16 * 256; i += 256){
    int rr = i >> 8, cc = i & 255;
    size_t o = (size_t)(b0 + rr) * 256 + cc;
    X[rr][cc] = hn1[o] + hn2[o];
  }
  __syncthreads();
  {
    const int n = tid;
    float a[16];
#pragma unroll
    for (int r = 0; r < 16; ++r) a[r] = fc1b[n];
    for (int k = 0; k < 256; ++k){
      float w = fc1wT[(size_t)k * 256 + n];
#pragma unroll
      for (int r = 0; r < 16; ++r) a[r] = fmaf(X[r][k], w, a[r]);
    }
#pragma unroll
    for (int r = 0; r < 16; ++r) Y[r][n] = sigm(a[r]);
  }
  __syncthreads();
  {
    const int m = tid & 63, rg = tid >> 6;
    float a2[4];
#pragma unroll
    for (int q = 0; q < 4; ++q) a2[q] = fc2b[m];
    for (int k = 0; k < 256; ++k){
      float w = fc2wT[(size_t)k * 64 + m];
#pragma unroll
      for (int q = 0; q < 4; ++q) a2[q] = fmaf(Y[rg * 4 + q][k], w, a2[q]);
    }
#pragma unroll
    for (int q = 0; q < 4; ++q)
      hidden[(size_t)(b0 + rg * 4 + q) * 128 + m] = sigm(a2[q]);
  }
  for (int i = tid; i < 16 * 64; i += 256){
    int rr = i >> 6, e = i & 63;
    hidden[(size_t)(b0 + rr) * 128 + 64 + e] = ne[(size_t)(b0 + rr) * 64 + e];
  }
}

// ================= decoder (all weights AGPR-resident) =================
__global__ __launch_bounds__(512) __attribute__((amdgpu_waves_per_eu(2, 2))) void k_dec(
    const float* __restrict__ edge, const float* __restrict__ hidden,
    const float* __restrict__ g1wih, const float* __restrict__ g1bih,
    const float* __restrict__ g1bhh, const u16* __restrict__ wd1,
    const float* __restrict__ g2bih, const float* __restrict__ g2bhh,
    const u16* __restrict__ wd2i, const u16* __restrict__ wd2h,
    const float* __restrict__ decw, const float* __restrict__ decb,
    float* __restrict__ out)
{
  const int b0 = blockIdx.x * 16;
  const int tid = threadIdx.x;
  const int wv  = tid >> 6;
  const int ln  = tid & 63;
  const int lr  = ln & 15;
  const int lk  = ln >> 4;

  __shared__ __align__(16) short h1bf[2][16 * 128];
  __shared__ __align__(16) short h2bf[2][16 * 64];
  __shared__ float part[2][4][16];

  bf16x8 W1[3][4];
  float wih1v[3], bih1v[3], bhh1v[3];
#pragma unroll
  for (int g = 0; g < 3; ++g){
    int n = g * 128 + wv * 16 + lr;
    wih1v[g] = g1wih[n];
    bih1v[g] = g1bih[n];
    bhh1v[g] = g1bhh[n];
#pragma unroll
    for (int kt = 0; kt < 4; ++kt){
      W1[g][kt] = *(const bf16x8*)(wd1 + ((size_t)(g * 4 + kt) * 512 + tid) * 8);
      SEED_A(W1[g][kt]);
    }
  }
  bf16x8 Wi2[3][4], Wh2[3][2];
  float bih2v[3] = {0,0,0}, bhh2v[3] = {0,0,0}, dwv = 0.f;
  const int jj = wv * 16 + lr;
  if (wv < 4){
    bool nv_ = (jj < 50);
    dwv = nv_ ? decw[jj] : 0.f;
#pragma unroll
    for (int g = 0; g < 3; ++g){
      bih2v[g] = nv_ ? g2bih[g * 50 + jj] : 0.f;
      bhh2v[g] = nv_ ? g2bhh[g * 50 + jj] : 0.f;
#pragma unroll
      for (int kt = 0; kt < 4; ++kt){
        Wi2[g][kt] = *(const bf16x8*)(wd2i + ((size_t)(g * 4 + kt) * 256 + tid) * 8);
        SEED_A(Wi2[g][kt]);
      }
#pragma unroll
      for (int kt = 0; kt < 2; ++kt){
        Wh2[g][kt] = *(const bf16x8*)(wd2h + ((size_t)(g * 2 + kt) * 256 + tid) * 8);
        SEED_A(Wh2[g][kt]);
      }
    }
  }
  float h1s[4], h2s[4] = {0.f, 0.f, 0.f, 0.f}, e4[4];
#pragma unroll
  for (int q = 0; q < 4; ++q){
    h1s[q] = hidden[(size_t)(b0 + lk * 4 + q) * 128 + wv * 16 + lr];
    int r = lk * 4 + q, j = wv * 16 + lr;
    *(short*)((char*)h1bf + r * 256 + ((2 * j) ^ ((r & 7) << 4))) = f2bf(h1s[q]);
    e4[q] = edge[(b0 + r) * NT + NT - 1];
  }
  for (int i = tid; i < 16 * 64; i += 512) h2bf[0][i] = 0;
  const float db = decb[0];
  __syncthreads();

  for (int s = 0; s < NT; ++s){
    const int p = s & 1;
    float res_q[4];
    if (s == 0){
#pragma unroll
      for (int q = 0; q < 4; ++q) res_q[q] = e4[q];
    } else {
#pragma unroll
      for (int q = 0; q < 4; ++q){
        int row = lk * 4 + q;
        float sum = part[p][0][row] + part[p][1][row] + part[p][2][row] + part[p][3][row] + db;
        res_q[q] = sigm(sum);
        if (wv == 0 && lr == 0) out[(size_t)(b0 + row) * NT + (s - 1)] = res_q[q];
      }
    }
    // ---- GRU1 (all waves) ----
    const char* h1r = (const char*)h1bf + p * (16 * 256);
    f32x4 ar, az, an;
#pragma unroll
    for (int q = 0; q < 4; ++q){ ar[q] = bhh1v[0]; az[q] = bhh1v[1]; an[q] = bhh1v[2]; }
#pragma unroll
    for (int kt = 0; kt < 4; ++kt){
      int off = lr * 256 + ((kt * 64 + lk * 16) ^ ((lr & 7) << 4));
      bf16x8 a = *(const bf16x8*)(h1r + off);
      MFMA_AG(ar, a, W1[0][kt]);
      MFMA_AG(az, a, W1[1][kt]);
      MFMA_AG(an, a, W1[2][kt]);
    }
    char* h1w = (char*)h1bf + (p ^ 1) * (16 * 256);
#pragma unroll
    for (int q = 0; q < 4; ++q){
      float res = res_q[q];
      float rv = sigm(fmaf(res, wih1v[0], bih1v[0]) + ar[q]);
      float zv = sigm(fmaf(res, wih1v[1], bih1v[1]) + az[q]);
      float nv = tanh_(fmaf(res, wih1v[2], bih1v[2]) + rv * an[q]);
      h1s[q] = (1.f - zv) * nv + zv * h1s[q];
      int r = lk * 4 + q, j = wv * 16 + lr;
      *(short*)(h1w + r * 256 + ((2 * j) ^ ((r & 7) << 4))) = f2bf(h1s[q]);
    }
    __syncthreads();   // A: new h1 visible
    // ---- GRU2 + dot (waves 0-3) ----
    if (wv < 4){
      f32x4 gi0, gi1, gi2v, gh0, gh1, gh2v;
#pragma unroll
      for (int q = 0; q < 4; ++q){
        gi0[q] = bih2v[0]; gi1[q] = bih2v[1]; gi2v[q] = bih2v[2];
        gh0[q] = bhh2v[0]; gh1[q] = bhh2v[1]; gh2v[q] = bhh2v[2];
      }
      const char* h1n = (const char*)h1bf + (p ^ 1) * (16 * 256);
#pragma unroll
      for (int kt = 0; kt < 4; ++kt){
        int off = lr * 256 + ((kt * 64 + lk * 16) ^ ((lr & 7) << 4));
        bf16x8 a = *(const bf16x8*)(h1n + off);
        MFMA_AG(gi0,  a, Wi2[0][kt]);
        MFMA_AG(gi1,  a, Wi2[1][kt]);
        MFMA_AG(gi2v, a, Wi2[2][kt]);
      }
      const char* h2r = (const char*)h2bf + p * (16 * 128);
#pragma unroll
      for (int kt = 0; kt < 2; ++kt){
        int off = lr * 128 + ((kt * 64 + lk * 16) ^ ((lr & 7) << 4));
        bf16x8 a = *(const bf16x8*)(h2r + off);
        MFMA_AG(gh0,  a, Wh2[0][kt]);
        MFMA_AG(gh1,  a, Wh2[1][kt]);
        MFMA_AG(gh2v, a, Wh2[2][kt]);
      }
      char* h2w = (char*)h2bf + (p ^ 1) * (16 * 128);
      float pd[4];
#pragma unroll
      for (int q = 0; q < 4; ++q){
        float r2 = sigm(gi0[q] + gh0[q]);
        float z2 = sigm(gi1[q] + gh1[q]);
        float n2 = tanh_(gi2v[q] + r2 * gh2v[q]);
        h2s[q] = (1.f - z2) * n2 + z2 * h2s[q];
        pd[q] = h2s[q] * dwv;
        int r = lk * 4 + q, j = wv * 16 + lr;
        *(short*)(h2w + r * 128 + ((2 * j) ^ ((r & 7) << 4))) = f2bf(h2s[q]);
      }
#pragma unroll
      for (int m = 1; m < 16; m <<= 1){
#pragma unroll
        for (int q = 0; q < 4; ++q) pd[q] += __shfl_xor(pd[q], m);
      }
      if (lr == 0){
#pragma unroll
        for (int q = 0; q < 4; ++q) part[p ^ 1][wv][lk * 4 + q] = pd[q];
      }
    }
    __syncthreads();   // B: h2/part ready
  }
  if (wv == 0 && lr == 0){
#pragma unroll
    for (int q = 0; q < 4; ++q){
      int row = lk * 4 + q;
      float sum = part[0][0][row] + part[0][1][row] + part[0][2][row] + part[0][3][row] + db;
      out[(size_t)(b0 + row) * NT + (NT - 1)] = sigm(sum);
    }
  }
}

// ================= launch =================
extern "C" void kernel_launch(void* const* d_in, const int* in_sizes, int n_in,
                              void* d_out, int out_size, void* d_ws, size_t ws_size,
                              hipStream_t stream)
{
  (void)in_sizes; (void)n_in; (void)out_size; (void)ws_size;
  const int*   nd    = (const int*)  d_in[0];
  const float* edge  = (const float*)d_in[1];
  const float* emb   = (const float*)d_in[2];
  const float* l1wf  = (const float*)d_in[3];
  const float* l1hf  = (const float*)d_in[4];
  const float* l1bf  = (const float*)d_in[5];
  const float* l1wb  = (const float*)d_in[6];
  const float* l1hb  = (const float*)d_in[7];
  const float* l1bb  = (const float*)d_in[8];
  const float* l2wf  = (const float*)d_in[9];
  const float* l2hf  = (const float*)d_in[10];
  const float* l2bf  = (const float*)d_in[11];
  const float* l2wb  = (const float*)d_in[12];
  const float* l2hb  = (const float*)d_in[13];
  const float* l2bb  = (const float*)d_in[14];
  const float* fc1w  = (const float*)d_in[15];
  const float* fc1b  = (const float*)d_in[16];
  const float* fc2w  = (const float*)d_in[17];
  const float* fc2b  = (const float*)d_in[18];
  const float* g1wih = (const float*)d_in[19];
  const float* g1whh = (const float*)d_in[20];
  const float* g1bih = (const float*)d_in[21];
  const float* g1bhh = (const float*)d_in[22];
  const float* g2wih = (const float*)d_in[23];
  const float* g2whh = (const float*)d_in[24];
  const float* g2bih = (const float*)d_in[25];
  const float* g2bhh = (const float*)d_in[26];
  const float* decw  = (const float*)d_in[27];
  const float* decb  = (const float*)d_in[28];

  char* ws = (char*)d_ws;
  u16*   h1out  = (u16*)ws;
  u16*   wd1    = (u16*)ws;
  u16*   wd2i   = (u16*)(ws + 98304);
  u16*   wd2h   = (u16*)(ws + 147456);
  float* fc1wT  = (float*)(ws + 262144);
  float* fc2wT  = (float*)(ws + 524288);
  float* hn1    = (float*)(ws + OFF_HN1);
  float* hn2    = (float*)(ws + OFF_HN2);
  u16*   wl2    = (u16*)(ws + OFF_ZC);
  u16*   wl1    = (u16*)(ws + OFF_ZC + 786432);
  float* ne     = (float*)(ws + OFF_ZC);
  float* hidden = (float*)(ws + OFF_ZC + 524288);

  prep_l12<<<dim3(256), dim3(256), 0, stream>>>(l1hf, l1hb, l2wf, l2hf, l2wb, l2hb, wl1, wl2);
  k_l1<<<dim3(256), dim3(512), 0, stream>>>(edge, wl1, l1wf, l1bf, l1wb, l1bb, h1out, hn1);
  k_l2<<<dim3(256), dim3(512), 0, stream>>>(h1out, wl2, l2bf, l2bb, hn2);
  prep_dec<<<dim3(42), dim3(256), 0, stream>>>(g1whh, g2wih, g2whh, wd1, wd2i, wd2h);
  prep_fcT<<<dim3(320), dim3(256), 0, stream>>>(fc1w, fc2w, fc1wT, fc2wT);
  k_node<<<dim3(512), dim3(256), 0, stream>>>(nd, emb, ne);
  k_fc<<<dim3(128), dim3(256), 0, stream>>>(hn1, hn2, fc1wT, fc1b, fc2wT, fc2b, ne, hidden);
  k_dec<<<dim3(128), dim3(512), 0, stream>>>(edge, hidden, g1wih, g1bih, g1bhh, wd1,
                                             g2bih, g2bhh, wd2i, wd2h, decw, decb,
                                             (float*)d_out);
}

// Round 7
// 1045.976 us; speedup vs baseline: 1.5256x; 1.0102x over previous
//
#include <hip/hip_runtime.h>
#include <stdint.h>

typedef short bf16x8 __attribute__((ext_vector_type(8)));
typedef float f32x4  __attribute__((ext_vector_type(4)));
typedef unsigned short u16;

#define NBATCH 2048
#define NT 200

// MFMA with weight operand FORCED into AGPR class at every use.
#define MFMA_AG(accv, av, wfrag) \
  asm("v_mfma_f32_16x16x32_bf16 %0, %1, %2, %0" : "+v"(accv) : "v"(av), "a"(wfrag))
#define SEED_A(x) asm volatile("" : "+a"(x))
// Barrier that waits LDS only (no vmcnt drain: global stores keep streaming).
#define BAR() asm volatile("s_waitcnt lgkmcnt(0)\n\ts_barrier" ::: "memory")

// ---- ws layout (total = 215,482,368 B) ----
#define OFF_HN1   209715200ull
#define OFF_HN2   211812352ull
#define OFF_ZC    213909504ull

__device__ __forceinline__ short f2bf(float f){
  union { float f; uint32_t u; } v; v.f = f;
  uint32_t u = v.u;
  u += 0x7fffu + ((u >> 16) & 1u);   // round-to-nearest-even
  return (short)(u >> 16);
}
// Fast activations: v_rcp instead of the ~12-op precise-division sequence.
__device__ __forceinline__ float sigm(float x){
  return __builtin_amdgcn_rcpf(1.0f + __expf(-x));
}
__device__ __forceinline__ float tanh_(float x){
  return fmaf(-2.0f, __builtin_amdgcn_rcpf(1.0f + __expf(2.0f * x)), 1.0f);
}

// ================= weight prep: fragment layouts (512-thread consumers) =================
__global__ void prep_l12(const float* __restrict__ l1hf, const float* __restrict__ l1hb,
                         const float* __restrict__ l2wf, const float* __restrict__ l2hf,
                         const float* __restrict__ l2wb, const float* __restrict__ l2hb,
                         u16* __restrict__ wl1, u16* __restrict__ wl2)
{
  int idx = blockIdx.x * 256 + threadIdx.x;     // 65536 total
  if (idx < 16384){                             // L1: 2*4*4*512
    int tid = idx & 511, r = idx >> 9;
    int kt = r & 3, g = (r >> 2) & 3, d = r >> 4;
    const float* whh = d ? l1hb : l1hf;
    int wv = tid >> 6, ln = tid & 63, lr = ln & 15, lk = ln >> 4;
    int n = g * 128 + wv * 16 + lr;
    const float* s = whh + (size_t)n * 128 + kt * 32 + lk * 8;
    bf16x8 w;
#pragma unroll
    for (int i = 0; i < 8; ++i) w[i] = f2bf(s[i]);
    *(bf16x8*)(wl1 + (size_t)idx * 8) = w;
  } else {                                      // L2: 2*4*12*512
    int j = idx - 16384;
    int tid = j & 511, r = j >> 9;              // r in 0..95
    int kt = r % 12, rg = r / 12;
    int g = rg & 3, d = rg >> 2;
    const float* wih = d ? l2wb : l2wf;
    const float* whh = d ? l2hb : l2hf;
    int wv = tid >> 6, ln = tid & 63, lr = ln & 15, lk = ln >> 4;
    int n = g * 128 + wv * 16 + lr;
    const float* s = (kt < 8) ? (wih + (size_t)n * 256 + kt * 32 + lk * 8)
                              : (whh + (size_t)n * 128 + (kt - 8) * 32 + lk * 8);
    bf16x8 w;
#pragma unroll
    for (int i = 0; i < 8; ++i) w[i] = f2bf(s[i]);
    *(bf16x8*)(wl2 + (size_t)j * 8) = w;
  }
}

// ===== merged: prep_dec (10752) + prep_fcT (81920) + k_node (131072) = 223744 = 874*256 =====
__global__ void prep2(const float* __restrict__ g1whh, const float* __restrict__ g2wih,
                      const float* __restrict__ g2whh,
                      const float* __restrict__ fc1w, const float* __restrict__ fc2w,
                      const int* __restrict__ nd, const float* __restrict__ emb,
                      u16* __restrict__ wd1, u16* __restrict__ wd2i, u16* __restrict__ wd2h,
                      float* __restrict__ fc1wT, float* __restrict__ fc2wT,
                      float* __restrict__ ne)
{
  int idx = blockIdx.x * 256 + threadIdx.x;
  if (idx < 6144){                              // W1: 3*4*512
    int tid = idx & 511, r = idx >> 9;
    int kt = r & 3, g = r >> 2;
    int wv = tid >> 6, ln = tid & 63, lr = ln & 15, lk = ln >> 4;
    int n = g * 128 + wv * 16 + lr;
    const float* s = g1whh + (size_t)n * 128 + kt * 32 + lk * 8;
    bf16x8 w;
#pragma unroll
    for (int i = 0; i < 8; ++i) w[i] = f2bf(s[i]);
    *(bf16x8*)(wd1 + (size_t)idx * 8) = w;
  } else if (idx < 9216){                       // Wi2: 3*4*256
    int j = idx - 6144;
    int tid = j & 255, r = j >> 8;
    int kt = r & 3, g = r >> 2;
    int wv = tid >> 6, ln = tid & 63, lr = ln & 15, lk = ln >> 4;
    int jj = wv * 16 + lr;
    bf16x8 w;
#pragma unroll
    for (int i = 0; i < 8; ++i){
      int k = kt * 32 + lk * 8 + i;
      w[i] = (jj < 50) ? f2bf(g2wih[(size_t)(g * 50 + jj) * 128 + k]) : (short)0;
    }
    *(bf16x8*)(wd2i + (size_t)j * 8) = w;
  } else if (idx < 10752){                      // Wh2: 3*2*256
    int j = idx - 9216;
    int tid = j & 255, r = j >> 8;
    int kt = r & 1, g = r >> 1;
    int wv = tid >> 6, ln = tid & 63, lr = ln & 15, lk = ln >> 4;
    int jj = wv * 16 + lr;
    bf16x8 w;
#pragma unroll
    for (int i = 0; i < 8; ++i){
      int k = kt * 32 + lk * 8 + i;
      w[i] = (jj < 50 && k < 50) ? f2bf(g2whh[(size_t)(g * 50 + jj) * 50 + k]) : (short)0;
    }
    *(bf16x8*)(wd2h + (size_t)j * 8) = w;
  } else if (idx < 10752 + 65536){              // fc1 transpose
    int j = idx - 10752;
    int n = j & 255, k = j >> 8;
    fc1wT[(size_t)k * 256 + n] = fc1w[(size_t)n * 256 + k];
  } else if (idx < 10752 + 81920){              // fc2 transpose
    int j = idx - 10752 - 65536;
    int m = j & 63, k = j >> 6;
    fc2wT[(size_t)k * 64 + m] = fc2w[(size_t)m * 256 + k];
  } else {                                      // node embedding mean
    int t = idx - 92672;
    int row = t >> 6, e = t & 63;
    int i0 = nd[row * 2], i1 = nd[row * 2 + 1];
    ne[t] = 0.5f * (emb[(size_t)i0 * 64 + e] + emb[(size_t)i1 * 64 + e]);
  }
}

// ================= BiLSTM layer 1 (W in AGPRs, wave-parity kt desync, lgkm barrier) =========
#define L1_KT(kt) { \
  int off = lr * 256 + (((kt) * 64 + lk * 16) ^ ((lr & 7) << 4)); \
  bf16x8 a = *(const bf16x8*)(hb + off); \
  MFMA_AG(acc[0], a, W[0][kt]); MFMA_AG(acc[1], a, W[1][kt]); \
  MFMA_AG(acc[2], a, W[2][kt]); MFMA_AG(acc[3], a, W[3][kt]); }

__global__ __launch_bounds__(512) __attribute__((amdgpu_waves_per_eu(2, 2))) void k_l1(
    const float* __restrict__ edge, const u16* __restrict__ wl1,
    const float* __restrict__ wih_f, const float* __restrict__ b_f,
    const float* __restrict__ wih_b, const float* __restrict__ b_b,
    u16* __restrict__ h1out, float* __restrict__ hn1)
{
  const int bid = blockIdx.x;
  const int dir = bid >> 7;
  const int b0  = (bid & 127) * 16;
  const float* wih = dir ? wih_b : wih_f;
  const float* bia = dir ? b_b  : b_f;

  const int tid = threadIdx.x;
  const int wv  = tid >> 6;
  const int ln  = tid & 63;
  const int lr  = ln & 15;
  const int lk  = ln >> 4;

  __shared__ __align__(16) short hbf[2][16 * 128];   // 256B rows, XOR-swizzled
  __shared__ float xall[16][NT];

  bf16x8 W[4][4];
  const u16* wb = wl1 + (size_t)dir * 16 * 512 * 8;
  float wv_[4], bv_[4];
#pragma unroll
  for (int g = 0; g < 4; ++g){
    int n = g * 128 + wv * 16 + lr;
    wv_[g] = wih[n];
    bv_[g] = bia[n];
#pragma unroll
    for (int kt = 0; kt < 4; ++kt){
      W[g][kt] = *(const bf16x8*)(wb + ((size_t)(g * 4 + kt) * 512 + tid) * 8);
      SEED_A(W[g][kt]);
    }
  }
  for (int i = tid; i < 16 * 128; i += 512) hbf[0][i] = 0;
  for (int i = tid; i < 16 * NT; i += 512){
    int r = i / NT, t = i - r * NT;
    xall[r][t] = edge[(b0 + r) * NT + t];
  }
  float cst[4] = {0.f, 0.f, 0.f, 0.f};
  float hseg[4] = {0.f, 0.f, 0.f, 0.f};
  __syncthreads();

  for (int s = 0; s < NT; ++s){
    const int p = s & 1;
    const int t = dir ? (NT - 1 - s) : s;

    const char* hb = (const char*)hbf + p * (16 * 256);
    f32x4 acc[4];
    float xq[4];
#pragma unroll
    for (int q = 0; q < 4; ++q) xq[q] = xall[lk * 4 + q][t];
#pragma unroll
    for (int g = 0; g < 4; ++g){
#pragma unroll
      for (int q = 0; q < 4; ++q) acc[g][q] = fmaf(xq[q], wv_[g], bv_[g]);
    }
    if (wv & 1){ L1_KT(2) L1_KT(3) L1_KT(0) L1_KT(1) }
    else       { L1_KT(0) L1_KT(1) L1_KT(2) L1_KT(3) }
    char* hbw = (char*)hbf + (p ^ 1) * (16 * 256);
#pragma unroll
    for (int q = 0; q < 4; ++q){
      float iv = sigm(acc[0][q]);
      float fv = sigm(acc[1][q]);
      float gv = tanh_(acc[2][q]);
      float ov = sigm(acc[3][q]);
      cst[q] = fv * cst[q] + iv * gv;
      hseg[q] = ov * tanh_(cst[q]);
      short hv = f2bf(hseg[q]);
      int r = lk * 4 + q, j = wv * 16 + lr;
      h1out[((size_t)t * NBATCH + b0 + r) * 256 + dir * 128 + j] = (u16)hv;
      *(short*)(hbw + r * 256 + ((2 * j) ^ ((r & 7) << 4))) = hv;
    }
    BAR();
  }
#pragma unroll
  for (int q = 0; q < 4; ++q)
    hn1[((size_t)dir * NBATCH + b0 + lk * 4 + q) * 128 + wv * 16 + lr] = hseg[q];
}

// ===== BiLSTM layer 2: fused K=384; 16 W-frags LDS + 32 W-frags AGPR; phase desync =====
#define L2_LDSKT(kt) { \
  int off = lr * 768 + (((kt) * 64 + lk * 16) ^ ((lr & 7) << 4)); \
  bf16x8 a = *(const bf16x8*)(ab + off); \
  bf16x8 w0 = *(const bf16x8*)&wlds[((size_t)(0 * 4 + (kt)) * 512 + tid) * 8]; \
  acc[0] = __builtin_amdgcn_mfma_f32_16x16x32_bf16(a, w0, acc[0], 0, 0, 0); \
  bf16x8 w1 = *(const bf16x8*)&wlds[((size_t)(1 * 4 + (kt)) * 512 + tid) * 8]; \
  acc[1] = __builtin_amdgcn_mfma_f32_16x16x32_bf16(a, w1, acc[1], 0, 0, 0); \
  bf16x8 w2 = *(const bf16x8*)&wlds[((size_t)(2 * 4 + (kt)) * 512 + tid) * 8]; \
  acc[2] = __builtin_amdgcn_mfma_f32_16x16x32_bf16(a, w2, acc[2], 0, 0, 0); \
  bf16x8 w3 = *(const bf16x8*)&wlds[((size_t)(3 * 4 + (kt)) * 512 + tid) * 8]; \
  acc[3] = __builtin_amdgcn_mfma_f32_16x16x32_bf16(a, w3, acc[3], 0, 0, 0); }

#define L2_AGKT(k8) { \
  int off = lr * 768 + (((4 + (k8)) * 64 + lk * 16) ^ ((lr & 7) << 4)); \
  bf16x8 a = *(const bf16x8*)(ab + off); \
  MFMA_AG(acc[0], a, Wa[0][k8]); MFMA_AG(acc[1], a, Wa[1][k8]); \
  MFMA_AG(acc[2], a, Wa[2][k8]); MFMA_AG(acc[3], a, Wa[3][k8]); }

__global__ __launch_bounds__(512) __attribute__((amdgpu_waves_per_eu(2, 2))) void k_l2(
    const u16* __restrict__ h1out, const u16* __restrict__ wl2,
    const float* __restrict__ b_f, const float* __restrict__ b_b,
    float* __restrict__ hn2)
{
  const int bid = blockIdx.x;
  const int dir = bid >> 7;
  const int b0  = (bid & 127) * 16;
  const float* bia = dir ? b_b : b_f;

  const int tid = threadIdx.x;
  const int wv  = tid >> 6;
  const int ln  = tid & 63;
  const int lr  = ln & 15;
  const int lk  = ln >> 4;

  __shared__ __align__(16) short wlds[16 * 512 * 8];   // 128KB: frags (g,kt<4), per-lane 16B
  __shared__ __align__(16) short Ab[2][16 * 384];      // 768B rows: x|h, swizzled

  const u16* wb = wl2 + (size_t)dir * 48 * 512 * 8;
#pragma unroll
  for (int f = 0; f < 16; ++f){
    int g = f >> 2, kt = f & 3;
    *(bf16x8*)&wlds[((size_t)f * 512 + tid) * 8] =
        *(const bf16x8*)(wb + ((size_t)(g * 12 + kt) * 512 + tid) * 8);
  }
  bf16x8 Wa[4][8];
  float bv_[4];
#pragma unroll
  for (int g = 0; g < 4; ++g){
    bv_[g] = bia[g * 128 + wv * 16 + lr];
#pragma unroll
    for (int k8 = 0; k8 < 8; ++k8){
      Wa[g][k8] = *(const bf16x8*)(wb + ((size_t)(g * 12 + 4 + k8) * 512 + tid) * 8);
      SEED_A(Wa[g][k8]);
    }
  }
  for (int i = tid; i < 16 * 128; i += 512){
    int r = i >> 7, j = i & 127;
    *(short*)((char*)Ab + r * 768 + ((512 + 2 * j) ^ ((r & 7) << 4))) = 0;
  }
  const int sr = tid >> 5, sg = tid & 31;
  {
    int t0 = dir ? NT - 1 : 0;
    bf16x8 v = *(const bf16x8*)(h1out + ((size_t)t0 * NBATCH + b0 + sr) * 256 + sg * 8);
    *(bf16x8*)((char*)Ab + sr * 768 + ((sg * 16) ^ ((sr & 7) << 4))) = v;
  }
  float cst[4] = {0.f, 0.f, 0.f, 0.f};
  float hseg[4] = {0.f, 0.f, 0.f, 0.f};
  __syncthreads();

  for (int s = 0; s < NT; ++s){
    const int p = s & 1;
    const int t = dir ? (NT - 1 - s) : s;
    const int tn = dir ? (t > 0 ? t - 1 : 0) : (t < NT - 1 ? t + 1 : NT - 1);
    bf16x8 xr = *(const bf16x8*)(h1out + ((size_t)tn * NBATCH + b0 + sr) * 256 + sg * 8);

    const char* ab = (const char*)Ab + p * (16 * 768);
    f32x4 acc[4];
#pragma unroll
    for (int g = 0; g < 4; ++g){
#pragma unroll
      for (int q = 0; q < 4; ++q) acc[g][q] = bv_[g];
    }
    // wave-parity desync: even waves hit LDS-kt phase first, odd waves AGPR-kt phase first
    if (wv & 1){
      L2_AGKT(0) L2_AGKT(1) L2_AGKT(2) L2_AGKT(3)
      L2_AGKT(4) L2_AGKT(5) L2_AGKT(6) L2_AGKT(7)
      L2_LDSKT(0) L2_LDSKT(1) L2_LDSKT(2) L2_LDSKT(3)
    } else {
      L2_LDSKT(0) L2_LDSKT(1) L2_LDSKT(2) L2_LDSKT(3)
      L2_AGKT(0) L2_AGKT(1) L2_AGKT(2) L2_AGKT(3)
      L2_AGKT(4) L2_AGKT(5) L2_AGKT(6) L2_AGKT(7)
    }
    char* abw = (char*)Ab + (p ^ 1) * (16 * 768);
#pragma unroll
    for (int q = 0; q < 4; ++q){
      float iv = sigm(acc[0][q]);
      float fv = sigm(acc[1][q]);
      float gv = tanh_(acc[2][q]);
      float ov = sigm(acc[3][q]);
      cst[q] = fv * cst[q] + iv * gv;
      hseg[q] = ov * tanh_(cst[q]);
      int r = lk * 4 + q, j = wv * 16 + lr;
      *(short*)(abw + r * 768 + ((512 + 2 * j) ^ ((r & 7) << 4))) = f2bf(hseg[q]);
    }
    *(bf16x8*)(abw + sr * 768 + ((sg * 16) ^ ((sr & 7) << 4))) = xr;
    BAR();
  }
#pragma unroll
  for (int q = 0; q < 4; ++q)
    hn2[((size_t)dir * NBATCH + b0 + lk * 4 + q) * 128 + wv * 16 + lr] = hseg[q];
}

// ================= FC =================
__global__ __launch_bounds__(256) void k_fc(
    const float* __restrict__ hn1, const float* __restrict__ hn2,
    const float* __restrict__ fc1wT, const float* __restrict__ fc1b,
    const float* __restrict__ fc2wT, const float* __restrict__ fc2b,
    const float* __restrict__ ne, float* __restrict__ hidden)
{
  __shared__ float X[16][256];
  __shared__ float Y[16][256];
  const int b0 = blockIdx.x * 16;
  const int tid = threadIdx.x;
  for (int i = tid; i < 16 * 256; i += 256){
    int rr = i >> 8, cc = i & 255;
    size_t o = (size_t)(b0 + rr) * 256 + cc;
    X[rr][cc] = hn1[o] + hn2[o];
  }
  __syncthreads();
  {
    const int n = tid;
    float a[16];
#pragma unroll
    for (int r = 0; r < 16; ++r) a[r] = fc1b[n];
    for (int k = 0; k < 256; ++k){
      float w = fc1wT[(size_t)k * 256 + n];
#pragma unroll
      for (int r = 0; r < 16; ++r) a[r] = fmaf(X[r][k], w, a[r]);
    }
#pragma unroll
    for (int r = 0; r < 16; ++r) Y[r][n] = sigm(a[r]);
  }
  __syncthreads();
  {
    const int m = tid & 63, rg = tid >> 6;
    float a2[4];
#pragma unroll
    for (int q = 0; q < 4; ++q) a2[q] = fc2b[m];
    for (int k = 0; k < 256; ++k){
      float w = fc2wT[(size_t)k * 64 + m];
#pragma unroll
      for (int q = 0; q < 4; ++q) a2[q] = fmaf(Y[rg * 4 + q][k], w, a2[q]);
    }
#pragma unroll
    for (int q = 0; q < 4; ++q)
      hidden[(size_t)(b0 + rg * 4 + q) * 128 + m] = sigm(a2[q]);
  }
  for (int i = tid; i < 16 * 64; i += 256){
    int rr = i >> 6, e = i & 63;
    hidden[(size_t)(b0 + rr) * 128 + 64 + e] = ne[(size_t)(b0 + rr) * 64 + e];
  }
}

// ================= decoder (weights AGPR-resident, kt desync, lgkm barriers) =================
#define D1_KT(kt) { \
  int off = lr * 256 + (((kt) * 64 + lk * 16) ^ ((lr & 7) << 4)); \
  bf16x8 a = *(const bf16x8*)(h1r + off); \
  MFMA_AG(ar, a, W1[0][kt]); MFMA_AG(az, a, W1[1][kt]); MFMA_AG(an, a, W1[2][kt]); }

#define D2_KT(kt) { \
  int off = lr * 256 + (((kt) * 64 + lk * 16) ^ ((lr & 7) << 4)); \
  bf16x8 a = *(const bf16x8*)(h1n + off); \
  MFMA_AG(gi0, a, Wi2[0][kt]); MFMA_AG(gi1, a, Wi2[1][kt]); MFMA_AG(gi2v, a, Wi2[2][kt]); }

__global__ __launch_bounds__(512) __attribute__((amdgpu_waves_per_eu(2, 2))) void k_dec(
    const float* __restrict__ edge, const float* __restrict__ hidden,
    const float* __restrict__ g1wih, const float* __restrict__ g1bih,
    const float* __restrict__ g1bhh, const u16* __restrict__ wd1,
    const float* __restrict__ g2bih, const float* __restrict__ g2bhh,
    const u16* __restrict__ wd2i, const u16* __restrict__ wd2h,
    const float* __restrict__ decw, const float* __restrict__ decb,
    float* __restrict__ out)
{
  const int b0 = blockIdx.x * 16;
  const int tid = threadIdx.x;
  const int wv  = tid >> 6;
  const int ln  = tid & 63;
  const int lr  = ln & 15;
  const int lk  = ln >> 4;

  __shared__ __align__(16) short h1bf[2][16 * 128];
  __shared__ __align__(16) short h2bf[2][16 * 64];
  __shared__ float part[2][4][16];

  bf16x8 W1[3][4];
  float wih1v[3], bih1v[3], bhh1v[3];
#pragma unroll
  for (int g = 0; g < 3; ++g){
    int n = g * 128 + wv * 16 + lr;
    wih1v[g] = g1wih[n];
    bih1v[g] = g1bih[n];
    bhh1v[g] = g1bhh[n];
#pragma unroll
    for (int kt = 0; kt < 4; ++kt){
      W1[g][kt] = *(const bf16x8*)(wd1 + ((size_t)(g * 4 + kt) * 512 + tid) * 8);
      SEED_A(W1[g][kt]);
    }
  }
  bf16x8 Wi2[3][4], Wh2[3][2];
  float bih2v[3] = {0,0,0}, bhh2v[3] = {0,0,0}, dwv = 0.f;
  const int jj = wv * 16 + lr;
  if (wv < 4){
    bool nv_ = (jj < 50);
    dwv = nv_ ? decw[jj] : 0.f;
#pragma unroll
    for (int g = 0; g < 3; ++g){
      bih2v[g] = nv_ ? g2bih[g * 50 + jj] : 0.f;
      bhh2v[g] = nv_ ? g2bhh[g * 50 + jj] : 0.f;
#pragma unroll
      for (int kt = 0; kt < 4; ++kt){
        Wi2[g][kt] = *(const bf16x8*)(wd2i + ((size_t)(g * 4 + kt) * 256 + tid) * 8);
        SEED_A(Wi2[g][kt]);
      }
#pragma unroll
      for (int kt = 0; kt < 2; ++kt){
        Wh2[g][kt] = *(const bf16x8*)(wd2h + ((size_t)(g * 2 + kt) * 256 + tid) * 8);
        SEED_A(Wh2[g][kt]);
      }
    }
  }
  float h1s[4], h2s[4] = {0.f, 0.f, 0.f, 0.f}, e4[4];
#pragma unroll
  for (int q = 0; q < 4; ++q){
    h1s[q] = hidden[(size_t)(b0 + lk * 4 + q) * 128 + wv * 16 + lr];
    int r = lk * 4 + q, j = wv * 16 + lr;
    *(short*)((char*)h1bf + r * 256 + ((2 * j) ^ ((r & 7) << 4))) = f2bf(h1s[q]);
    e4[q] = edge[(b0 + r) * NT + NT - 1];
  }
  for (int i = tid; i < 16 * 64; i += 512) h2bf[0][i] = 0;
  const float db = decb[0];
  __syncthreads();

  for (int s = 0; s < NT; ++s){
    const int p = s & 1;
    float res_q[4];
    if (s == 0){
#pragma unroll
      for (int q = 0; q < 4; ++q) res_q[q] = e4[q];
    } else {
#pragma unroll
      for (int q = 0; q < 4; ++q){
        int row = lk * 4 + q;
        float sum = part[p][0][row] + part[p][1][row] + part[p][2][row] + part[p][3][row] + db;
        res_q[q] = sigm(sum);
        if (wv == 0 && lr == 0) out[(size_t)(b0 + row) * NT + (s - 1)] = res_q[q];
      }
    }
    // ---- GRU1 (all waves) ----
    const char* h1r = (const char*)h1bf + p * (16 * 256);
    f32x4 ar, az, an;
#pragma unroll
    for (int q = 0; q < 4; ++q){ ar[q] = bhh1v[0]; az[q] = bhh1v[1]; an[q] = bhh1v[2]; }
    if (wv & 1){ D1_KT(2) D1_KT(3) D1_KT(0) D1_KT(1) }
    else       { D1_KT(0) D1_KT(1) D1_KT(2) D1_KT(3) }
    char* h1w = (char*)h1bf + (p ^ 1) * (16 * 256);
#pragma unroll
    for (int q = 0; q < 4; ++q){
      float res = res_q[q];
      float rv = sigm(fmaf(res, wih1v[0], bih1v[0]) + ar[q]);
      float zv = sigm(fmaf(res, wih1v[1], bih1v[1]) + az[q]);
      float nv = tanh_(fmaf(res, wih1v[2], bih1v[2]) + rv * an[q]);
      h1s[q] = (1.f - zv) * nv + zv * h1s[q];
      int r = lk * 4 + q, j = wv * 16 + lr;
      *(short*)(h1w + r * 256 + ((2 * j) ^ ((r & 7) << 4))) = f2bf(h1s[q]);
    }
    BAR();             // A: new h1 visible
    // ---- GRU2 + dot (waves 0-3) ----
    if (wv < 4){
      f32x4 gi0, gi1, gi2v, gh0, gh1, gh2v;
#pragma unroll
      for (int q = 0; q < 4; ++q){
        gi0[q] = bih2v[0]; gi1[q] = bih2v[1]; gi2v[q] = bih2v[2];
        gh0[q] = bhh2v[0]; gh1[q] = bhh2v[1]; gh2v[q] = bhh2v[2];
      }
      const char* h1n = (const char*)h1bf + (p ^ 1) * (16 * 256);
      if (wv & 1){ D2_KT(2) D2_KT(3) D2_KT(0) D2_KT(1) }
      else       { D2_KT(0) D2_KT(1) D2_KT(2) D2_KT(3) }
      const char* h2r = (const char*)h2bf + p * (16 * 128);
#pragma unroll
      for (int kt = 0; kt < 2; ++kt){
        int off = lr * 128 + ((kt * 64 + lk * 16) ^ ((lr & 7) << 4));
        bf16x8 a = *(const bf16x8*)(h2r + off);
        MFMA_AG(gh0,  a, Wh2[0][kt]);
        MFMA_AG(gh1,  a, Wh2[1][kt]);
        MFMA_AG(gh2v, a, Wh2[2][kt]);
      }
      char* h2w = (char*)h2bf + (p ^ 1) * (16 * 128);
      float pd[4];
#pragma unroll
      for (int q = 0; q < 4; ++q){
        float r2 = sigm(gi0[q] + gh0[q]);
        float z2 = sigm(gi1[q] + gh1[q]);
        float n2 = tanh_(gi2v[q] + r2 * gh2v[q]);
        h2s[q] = (1.f - z2) * n2 + z2 * h2s[q];
        pd[q] = h2s[q] * dwv;
        int r = lk * 4 + q, j = wv * 16 + lr;
        *(short*)(h2w + r * 128 + ((2 * j) ^ ((r & 7) << 4))) = f2bf(h2s[q]);
      }
#pragma unroll
      for (int m = 1; m < 16; m <<= 1){
#pragma unroll
        for (int q = 0; q < 4; ++q) pd[q] += __shfl_xor(pd[q], m);
      }
      if (lr == 0){
#pragma unroll
        for (int q = 0; q < 4; ++q) part[p ^ 1][wv][lk * 4 + q] = pd[q];
      }
    }
    BAR();             // B: h2/part ready
  }
  if (wv == 0 && lr == 0){
#pragma unroll
    for (int q = 0; q < 4; ++q){
      int row = lk * 4 + q;
      float sum = part[0][0][row] + part[0][1][row] + part[0][2][row] + part[0][3][row] + db;
      out[(size_t)(b0 + row) * NT + (NT - 1)] = sigm(sum);
    }
  }
}

// ================= launch =================
extern "C" void kernel_launch(void* const* d_in, const int* in_sizes, int n_in,
                              void* d_out, int out_size, void* d_ws, size_t ws_size,
                              hipStream_t stream)
{
  (void)in_sizes; (void)n_in; (void)out_size; (void)ws_size;
  const int*   nd    = (const int*)  d_in[0];
  const float* edge  = (const float*)d_in[1];
  const float* emb   = (const float*)d_in[2];
  const float* l1wf  = (const float*)d_in[3];
  const float* l1hf  = (const float*)d_in[4];
  const float* l1bf  = (const float*)d_in[5];
  const float* l1wb  = (const float*)d_in[6];
  const float* l1hb  = (const float*)d_in[7];
  const float* l1bb  = (const float*)d_in[8];
  const float* l2wf  = (const float*)d_in[9];
  const float* l2hf  = (const float*)d_in[10];
  const float* l2bf  = (const float*)d_in[11];
  const float* l2wb  = (const float*)d_in[12];
  const float* l2hb  = (const float*)d_in[13];
  const float* l2bb  = (const float*)d_in[14];
  const float* fc1w  = (const float*)d_in[15];
  const float* fc1b  = (const float*)d_in[16];
  const float* fc2w  = (const float*)d_in[17];
  const float* fc2b  = (const float*)d_in[18];
  const float* g1wih = (const float*)d_in[19];
  const float* g1whh = (const float*)d_in[20];
  const float* g1bih = (const float*)d_in[21];
  const float* g1bhh = (const float*)d_in[22];
  const float* g2wih = (const float*)d_in[23];
  const float* g2whh = (const float*)d_in[24];
  const float* g2bih = (const float*)d_in[25];
  const float* g2bhh = (const float*)d_in[26];
  const float* decw  = (const float*)d_in[27];
  const float* decb  = (const float*)d_in[28];

  char* ws = (char*)d_ws;
  u16*   h1out  = (u16*)ws;
  u16*   wd1    = (u16*)ws;
  u16*   wd2i   = (u16*)(ws + 98304);
  u16*   wd2h   = (u16*)(ws + 147456);
  float* fc1wT  = (float*)(ws + 262144);
  float* fc2wT  = (float*)(ws + 524288);
  float* hn1    = (float*)(ws + OFF_HN1);
  float* hn2    = (float*)(ws + OFF_HN2);
  u16*   wl2    = (u16*)(ws + OFF_ZC);
  u16*   wl1    = (u16*)(ws + OFF_ZC + 786432);
  float* ne     = (float*)(ws + OFF_ZC);
  float* hidden = (float*)(ws + OFF_ZC + 524288);

  prep_l12<<<dim3(256), dim3(256), 0, stream>>>(l1hf, l1hb, l2wf, l2hf, l2wb, l2hb, wl1, wl2);
  k_l1<<<dim3(256), dim3(512), 0, stream>>>(edge, wl1, l1wf, l1bf, l1wb, l1bb, h1out, hn1);
  k_l2<<<dim3(256), dim3(512), 0, stream>>>(h1out, wl2, l2bf, l2bb, hn2);
  prep2<<<dim3(874), dim3(256), 0, stream>>>(g1whh, g2wih, g2whh, fc1w, fc2w, nd, emb,
                                             wd1, wd2i, wd2h, fc1wT, fc2wT, ne);
  k_fc<<<dim3(128), dim3(256), 0, stream>>>(hn1, hn2, fc1wT, fc1b, fc2wT, fc2b, ne, hidden);
  k_dec<<<dim3(128), dim3(512), 0, stream>>>(edge, hidden, g1wih, g1bih, g1bhh, wd1,
                                             g2bih, g2bhh, wd2i, wd2h, decw, decb,
                                             (float*)d_out);
}